// Round 1
// baseline (61.489 us; speedup 1.0000x reference)
//
#include <hip/hip_runtime.h>

// 6-qubit statevector, fully real-arithmetic simulation (see analysis):
// RY gates are real; the CCC-Y block only touches the q3q4q5=111 sector and
// reduces to a sign+reversal permutation with a global factor of i that is
// invisible to the final |.|^2 measurement.
//
// Index convention (matches reference C-order flatten of (2,)*6 with qubit 0
// leftmost): idx = q0*32 + q1*16 + q2*8 + q3*4 + q4*2 + q5.
// Target qubit q -> bit TB = 1<<(5-q). Control qubit c -> mask bit 1<<(5-c).

template <int TB, int CM>
__device__ __forceinline__ void ry_g(float* st, float c, float s) {
#pragma unroll
    for (int i = 0; i < 64; ++i) {
        if (i & TB) continue;             // i is the bit=0 element of the pair
        if ((i & CM) != CM) continue;     // controls must be 1
        float a0 = st[i];
        float a1 = st[i + TB];
        st[i]      = fmaf(c, a0, -s * a1);
        st[i + TB] = fmaf(s, a0,  c * a1);
    }
}

__global__ __launch_bounds__(256) void pnn_kernel(const float* __restrict__ x,
                                                  const float* __restrict__ p,
                                                  float* __restrict__ out,
                                                  int n) {
    int b = blockIdx.x * blockDim.x + threadIdx.x;
    if (b >= n) return;
    float xv = x[b];

    float st[64];
#pragma unroll
    for (int i = 0; i < 64; ++i) st[i] = 0.0f;
    st[0] = 1.0f;

    float c, s;
    auto cs = [&](float th) { __sincosf(th * 0.5f, &s, &c); };

    // -- data encoding block 1 (qubits 0,1,2) --
    cs(xv * 3.0f); ry_g<32, 0>(st, c, s);
    cs(xv * 9.0f); ry_g<16, 0>(st, c, s);
    cs(xv);        ry_g<8, 0>(st, c, s);
    // -- variational layer on qubits 0..2 --
    cs(p[0]); ry_g<32, 0>(st, c, s);
    cs(p[1]); ry_g<16, 0>(st, c, s);
    cs(p[2]); ry_g<8, 0>(st, c, s);
    // -- controlled rotations onto qubit 3 --
    cs(p[3]); ry_g<4, 8>(st, c, s);    // ctrl q2
    cs(p[4]); ry_g<4, 16>(st, c, s);   // ctrl q1
    cs(p[5]); ry_g<4, 32>(st, c, s);   // ctrl q0
    cs(p[6]); ry_g<4, 0>(st, c, s);
    // -- qubit 4 --
    cs(p[7]);  ry_g<2, 8>(st, c, s);
    cs(p[8]);  ry_g<2, 16>(st, c, s);
    cs(p[9]);  ry_g<2, 32>(st, c, s);
    cs(p[10]); ry_g<2, 0>(st, c, s);
    // -- qubit 5 --
    cs(p[11]); ry_g<1, 8>(st, c, s);
    cs(p[12]); ry_g<1, 16>(st, c, s);
    cs(p[13]); ry_g<1, 32>(st, c, s);
    cs(p[14]); ry_g<1, 0>(st, c, s);
    // -- RY(0.5) on 3,4,5 (one sincos, three gates) --
    cs(0.5f);
    ry_g<4, 0>(st, c, s); ry_g<2, 0>(st, c, s); ry_g<1, 0>(st, c, s);
    // -- entangling block among qubits 3,4,5 --
    cs(p[15]); ry_g<2, 4>(st, c, s);   // t4 c3
    cs(p[16]); ry_g<1, 4>(st, c, s);   // t5 c3
    cs(p[17]); ry_g<4, 2>(st, c, s);   // t3 c4
    cs(p[18]); ry_g<1, 2>(st, c, s);   // t5 c4
    cs(p[19]); ry_g<4, 1>(st, c, s);   // t3 c5
    cs(p[20]); ry_g<2, 1>(st, c, s);   // t4 c5
    cs(p[21]); ry_g<4, 0>(st, c, s);
    cs(p[22]); ry_g<2, 0>(st, c, s);
    cs(p[23]); ry_g<1, 0>(st, c, s);

    // -- triply-controlled Y on qubits 0,1,2 (controls 3,4,5 all = 1) --
    // Sector indices: i = 8*j + 7, j = q0*4+q1*2+q2. Net effect of Y0*Y1*Y2
    // is i * (sign(j) * old[7-j]); the overall i drops out of |.|^2 since this
    // sector never mixes with the others afterwards.
    {
        float o[8];
#pragma unroll
        for (int j = 0; j < 8; ++j) o[j] = st[8 * j + 7];
        st[8 * 0 + 7] =  o[7];
        st[8 * 1 + 7] = -o[6];
        st[8 * 2 + 7] = -o[5];
        st[8 * 3 + 7] =  o[4];
        st[8 * 4 + 7] = -o[3];
        st[8 * 5 + 7] =  o[2];
        st[8 * 6 + 7] =  o[1];
        st[8 * 7 + 7] = -o[0];
    }

    // -- data encoding block 2 --
    cs(xv * 7.0f);  ry_g<32, 0>(st, c, s);
    cs(xv * 17.0f); ry_g<16, 0>(st, c, s);
    cs(xv);         ry_g<8, 0>(st, c, s);
    cs(p[24]); ry_g<32, 0>(st, c, s);
    cs(p[25]); ry_g<16, 0>(st, c, s);
    cs(p[26]); ry_g<8, 0>(st, c, s);
    cs(-0.5f);
    ry_g<32, 0>(st, c, s); ry_g<16, 0>(st, c, s); ry_g<8, 0>(st, c, s);
    // -- entangling block among qubits 0,1,2 --
    cs(p[27]); ry_g<16, 32>(st, c, s); // t1 c0
    cs(p[28]); ry_g<8, 32>(st, c, s);  // t2 c0
    cs(p[29]); ry_g<32, 16>(st, c, s); // t0 c1
    cs(p[30]); ry_g<8, 16>(st, c, s);  // t2 c1
    cs(p[31]); ry_g<32, 8>(st, c, s);  // t0 c2
    cs(p[32]); ry_g<16, 8>(st, c, s);  // t1 c2
    cs(p[33]); ry_g<32, 0>(st, c, s);
    cs(p[34]); ry_g<16, 0>(st, c, s);
    cs(p[35]); ry_g<8, 0>(st, c, s);

    // p000: q0q1q2 = 000 -> indices 0..7 ; p111: 111 -> indices 56..63.
    float p000 = 0.0f, p111 = 0.0f;
#pragma unroll
    for (int i = 0; i < 8; ++i)   p000 = fmaf(st[i], st[i], p000);
#pragma unroll
    for (int i = 56; i < 64; ++i) p111 = fmaf(st[i], st[i], p111);
    out[b] = (p111 - p000) * 2.0f;
}

extern "C" void kernel_launch(void* const* d_in, const int* in_sizes, int n_in,
                              void* d_out, int out_size, void* d_ws, size_t ws_size,
                              hipStream_t stream) {
    const float* x = (const float*)d_in[0];
    const float* p = (const float*)d_in[1];
    float* out = (float*)d_out;
    int n = in_sizes[0];
    int block = 256;
    int grid = (n + block - 1) / block;
    pnn_kernel<<<grid, block, 0, stream>>>(x, p, out, n);
}